// Round 1
// baseline (9212.688 us; speedup 1.0000x reference)
//
#include <hip/hip_runtime.h>
#include <cmath>

#define BB 8
#define HS 128
#define WS 128
#define CC 192
#define NHEAD 6
#define WIN 8
#define SHIFT_ 4
#define LL (HS*WS)
#define HIDD (4*CC)

// ---------------- weight transpose for spade convs ----------------
// wt[(tap*128+ch)*384 + c]; c<192 -> wg[c][ch][tap], c>=192 -> wb[c-192][ch][tap]
__global__ void k_trans_w(const float* __restrict__ wg, const float* __restrict__ wb,
                          float* __restrict__ wt) {
    int idx = blockIdx.x * 256 + threadIdx.x;
    if (idx >= 1152 * 384) return;
    int c = idx % 384;
    int k = idx / 384;
    int ch = k % 128;
    int tap = k / 128;
    const float* src = (c < 192) ? wg : wb;
    int cc = (c < 192) ? c : (c - 192);
    wt[idx] = src[(cc * 128 + ch) * 9 + tap];
}

// ---------------- conv1: src [B,1,H,W] -> a [B,H,W,128], leaky_relu ----------------
__global__ void k_conv1(const float* __restrict__ src, const float* __restrict__ w1,
                        const float* __restrict__ b1, float* __restrict__ a) {
    int c = threadIdx.x;               // 128 threads
    int blk = blockIdx.x;              // b*Hs*(Ws/16)
    int xseg = blk % (WS / 16);
    int tmp = blk / (WS / 16);
    int y = tmp % HS;
    int b = tmp / HS;
    float w[9];
#pragma unroll
    for (int t = 0; t < 9; t++) w[t] = w1[c * 9 + t];
    float bias = b1[c];
    const float* sp = src + (size_t)b * HS * WS;
    for (int px = 0; px < 16; px++) {
        int x = xseg * 16 + px;
        float acc = bias;
#pragma unroll
        for (int dy = 0; dy < 3; dy++) {
            int yy = y + dy - 1;
            if (yy < 0 || yy >= HS) continue;
#pragma unroll
            for (int dx = 0; dx < 3; dx++) {
                int xx = x + dx - 1;
                if (xx < 0 || xx >= WS) continue;
                acc += sp[yy * WS + xx] * w[dy * 3 + dx];
            }
        }
        a[(((size_t)b * HS + y) * WS + x) * 128 + c] = acc > 0.f ? acc : 0.01f * acc;
    }
}

// ---------------- LN stats per token ----------------
__global__ void k_lnstats(const float* __restrict__ x, float* __restrict__ mu,
                          float* __restrict__ rs) {
    int tok = blockIdx.x * 4 + (threadIdx.x >> 6);
    int lane = threadIdx.x & 63;
    const float* xp = x + (size_t)tok * CC;
    float v0 = xp[lane], v1 = xp[lane + 64], v2 = xp[lane + 128];
    float s = v0 + v1 + v2;
#pragma unroll
    for (int off = 32; off; off >>= 1) s += __shfl_xor(s, off);
    float m = s * (1.f / CC);
    float e0 = v0 - m, e1 = v1 - m, e2 = v2 - m;
    float s2 = e0 * e0 + e1 * e1 + e2 * e2;
#pragma unroll
    for (int off = 32; off; off >>= 1) s2 += __shfl_xor(s2, off);
    if (lane == 0) {
        mu[tok] = m;
        rs[tok] = rsqrtf(s2 * (1.f / CC) + 1e-5f);
    }
}

// ---------------- fused SPADE: h = ln(x)*(1+gamma)+beta ----------------
#define PSTR 136
__device__ __forceinline__ float f4c(const float4& v, int kk) {
    return kk == 0 ? v.x : (kk == 1 ? v.y : (kk == 2 ? v.z : v.w));
}
__global__ __launch_bounds__(256, 2) void k_spade(
    const float* __restrict__ x, const float* __restrict__ mu, const float* __restrict__ rs,
    const float* __restrict__ g, const float* __restrict__ bta,
    const float* __restrict__ bg, const float* __restrict__ bb,
    const float* __restrict__ a, const float* __restrict__ wt, float* __restrict__ h) {
    __shared__ float patch[100 * PSTR];
    int blk = blockIdx.x;
    int bx = blk & 15;
    int by = (blk >> 4) & 15;
    int b = blk >> 8;
    int tid = threadIdx.x;
    // stage 10x10x128 patch of a
    for (int i = tid; i < 100 * 32; i += 256) {
        int pos = i >> 5, seg = i & 31;
        int py = pos / 10, px = pos % 10;
        int gy = by * 8 + py - 1, gx = bx * 8 + px - 1;
        float4 v = make_float4(0.f, 0.f, 0.f, 0.f);
        if (gy >= 0 && gy < HS && gx >= 0 && gx < WS)
            v = *(const float4*)&a[(((size_t)b * HS + gy) * WS + gx) * 128 + seg * 4];
        *(float4*)&patch[pos * PSTR + seg * 4] = v;
    }
    __syncthreads();
    int tn = tid & 15, tm = tid >> 4;
    float accg[4][12], accb[4][12];
#pragma unroll
    for (int q = 0; q < 4; q++)
#pragma unroll
        for (int u = 0; u < 12; u++) {
            accg[q][u] = bg[tn * 12 + u];
            accb[q][u] = bb[tn * 12 + u];
        }
    for (int tap = 0; tap < 9; tap++) {
        int dy = tap / 3, dx = tap % 3;
        int pos[4];
#pragma unroll
        for (int q = 0; q < 4; q++) {
            int p = tm + 16 * q;
            pos[q] = ((p >> 3) + dy) * 10 + (p & 7) + dx;
        }
        const float* wtap = wt + (size_t)(tap * 128) * 384;
#pragma unroll 2
        for (int c4 = 0; c4 < 32; c4++) {
            float4 av[4];
#pragma unroll
            for (int q = 0; q < 4; q++)
                av[q] = *(const float4*)&patch[pos[q] * PSTR + c4 * 4];
#pragma unroll
            for (int kk = 0; kk < 4; kk++) {
                const float* wr = wtap + (size_t)(c4 * 4 + kk) * 384 + tn * 12;
                float4 g0 = *(const float4*)(wr);
                float4 g1 = *(const float4*)(wr + 4);
                float4 g2 = *(const float4*)(wr + 8);
                float4 b0 = *(const float4*)(wr + 192);
                float4 b1 = *(const float4*)(wr + 196);
                float4 b2 = *(const float4*)(wr + 200);
#pragma unroll
                for (int q = 0; q < 4; q++) {
                    float av_ = f4c(av[q], kk);
                    accg[q][0] += av_ * g0.x; accg[q][1] += av_ * g0.y;
                    accg[q][2] += av_ * g0.z; accg[q][3] += av_ * g0.w;
                    accg[q][4] += av_ * g1.x; accg[q][5] += av_ * g1.y;
                    accg[q][6] += av_ * g1.z; accg[q][7] += av_ * g1.w;
                    accg[q][8] += av_ * g2.x; accg[q][9] += av_ * g2.y;
                    accg[q][10] += av_ * g2.z; accg[q][11] += av_ * g2.w;
                    accb[q][0] += av_ * b0.x; accb[q][1] += av_ * b0.y;
                    accb[q][2] += av_ * b0.z; accb[q][3] += av_ * b0.w;
                    accb[q][4] += av_ * b1.x; accb[q][5] += av_ * b1.y;
                    accb[q][6] += av_ * b1.z; accb[q][7] += av_ * b1.w;
                    accb[q][8] += av_ * b2.x; accb[q][9] += av_ * b2.y;
                    accb[q][10] += av_ * b2.z; accb[q][11] += av_ * b2.w;
                }
            }
        }
    }
    // epilogue
#pragma unroll
    for (int q = 0; q < 4; q++) {
        int p = tm + 16 * q;
        int gy = by * 8 + (p >> 3), gx = bx * 8 + (p & 7);
        size_t l = (size_t)b * LL + gy * WS + gx;
        float m = mu[l], r = rs[l];
        const float* xp = x + l * CC + tn * 12;
        float* hp = h + l * CC + tn * 12;
#pragma unroll
        for (int u = 0; u < 12; u++) {
            int c = tn * 12 + u;
            float n = (xp[u] - m) * r * g[c] + bta[c];
            hp[u] = n * (1.f + accg[q][u]) + accb[q][u];
        }
    }
}

// ---------------- fused window attention + proj + residual ----------------
#define XSTR 196
#define QSTR 36
#define SSTR 68
__global__ __launch_bounds__(256, 1) void k_attn(
    const float* __restrict__ h, const float* __restrict__ x,
    const float* __restrict__ qkv_w, const float* __restrict__ qkv_b,
    const float* __restrict__ rpb, const float* __restrict__ proj_w,
    const float* __restrict__ proj_b, float* __restrict__ x1) {
    __shared__ float Xs[64 * XSTR];
    __shared__ float Os[64 * XSTR];
    __shared__ float qs[64 * QSTR];
    __shared__ float ks_[64 * QSTR];
    __shared__ float vs[64 * QSTR];
    __shared__ float ss[64 * SSTR];
    int blk = blockIdx.x;
    int ww = blk & 15, wh = (blk >> 4) & 15, b = blk >> 8;
    int tid = threadIdx.x, tn = tid & 15, tm = tid >> 4;
    // stage X (shifted window gather)
    for (int i = tid; i < 64 * 48; i += 256) {
        int n = i / 48, seg = i % 48;
        int yy = ((wh << 3) + (n >> 3) + SHIFT_) & 127;
        int xx = ((ww << 3) + (n & 7) + SHIFT_) & 127;
        *(float4*)&Xs[n * XSTR + seg * 4] =
            *(const float4*)&h[((size_t)b * LL + yy * WS + xx) * CC + seg * 4];
    }
    __syncthreads();
    for (int hd = 0; hd < NHEAD; hd++) {
        // qkv for this head
        float acc[4][6];
#pragma unroll
        for (int q = 0; q < 4; q++)
#pragma unroll
            for (int u = 0; u < 6; u++)
                acc[q][u] = qkv_b[(u >> 1) * 192 + hd * 32 + tn + ((u & 1) << 4)];
        for (int k = 0; k < 192; k++) {
            float xv[4];
#pragma unroll
            for (int q = 0; q < 4; q++) xv[q] = Xs[(tm + 16 * q) * XSTR + k];
            const float* wr = qkv_w + (size_t)k * 576 + hd * 32 + tn;
            float w0 = wr[0], w1 = wr[16], w2 = wr[192], w3 = wr[208], w4 = wr[384], w5 = wr[400];
#pragma unroll
            for (int q = 0; q < 4; q++) {
                acc[q][0] += xv[q] * w0; acc[q][1] += xv[q] * w1;
                acc[q][2] += xv[q] * w2; acc[q][3] += xv[q] * w3;
                acc[q][4] += xv[q] * w4; acc[q][5] += xv[q] * w5;
            }
        }
#pragma unroll
        for (int q = 0; q < 4; q++) {
            int row = tm + 16 * q;
            qs[row * QSTR + tn] = acc[q][0] * 0.17677669529663687f;
            qs[row * QSTR + tn + 16] = acc[q][1] * 0.17677669529663687f;
            ks_[row * QSTR + tn] = acc[q][2];
            ks_[row * QSTR + tn + 16] = acc[q][3];
            vs[row * QSTR + tn] = acc[q][4];
            vs[row * QSTR + tn + 16] = acc[q][5];
        }
        __syncthreads();
        // scores + rpb + mask
        float sacc[4][4] = {};
        for (int k = 0; k < 32; k++) {
            float qv[4], kv[4];
#pragma unroll
            for (int q = 0; q < 4; q++) qv[q] = qs[(tm + 16 * q) * QSTR + k];
#pragma unroll
            for (int u = 0; u < 4; u++) kv[u] = ks_[(tn + 16 * u) * QSTR + k];
#pragma unroll
            for (int q = 0; q < 4; q++)
#pragma unroll
                for (int u = 0; u < 4; u++) sacc[q][u] += qv[q] * kv[u];
        }
#pragma unroll
        for (int q = 0; q < 4; q++) {
            int n = tm + 16 * q;
            int i1 = n >> 3, j1 = n & 7;
            int yr1 = (wh << 3) + i1, xr1 = (ww << 3) + j1;
            int lh1 = (yr1 < 120) ? 0 : ((yr1 < 124) ? 1 : 2);
            int lw1 = (xr1 < 120) ? 0 : ((xr1 < 124) ? 1 : 2);
#pragma unroll
            for (int u = 0; u < 4; u++) {
                int m = tn + 16 * u;
                int i2 = m >> 3, j2 = m & 7;
                int rel = (i1 - i2 + 7) * 15 + (j1 - j2 + 7);
                float bias = rpb[rel * NHEAD + hd];
                int yr2 = (wh << 3) + i2, xr2 = (ww << 3) + j2;
                int lh2 = (yr2 < 120) ? 0 : ((yr2 < 124) ? 1 : 2);
                int lw2 = (xr2 < 120) ? 0 : ((xr2 < 124) ? 1 : 2);
                float msk = (lh1 == lh2 && lw1 == lw2) ? 0.f : -100.f;
                ss[n * SSTR + m] = sacc[q][u] + bias + msk;
            }
        }
        __syncthreads();
        // softmax (4 lanes per row)
        {
            int r = tid >> 2, lg = tid & 3;
            float ev[16];
            float mx = -3.4e38f;
#pragma unroll
            for (int t = 0; t < 16; t++) {
                ev[t] = ss[r * SSTR + lg + 4 * t];
                mx = fmaxf(mx, ev[t]);
            }
            mx = fmaxf(mx, __shfl_xor(mx, 1));
            mx = fmaxf(mx, __shfl_xor(mx, 2));
            float sm = 0.f;
#pragma unroll
            for (int t = 0; t < 16; t++) {
                ev[t] = expf(ev[t] - mx);
                sm += ev[t];
            }
            sm += __shfl_xor(sm, 1);
            sm += __shfl_xor(sm, 2);
            float inv = 1.f / sm;
#pragma unroll
            for (int t = 0; t < 16; t++) ss[r * SSTR + lg + 4 * t] = ev[t] * inv;
        }
        __syncthreads();
        // PV
        float oacc[4][2] = {};
        for (int k = 0; k < 64; k++) {
            float pv[4];
#pragma unroll
            for (int q = 0; q < 4; q++) pv[q] = ss[(tm + 16 * q) * SSTR + k];
            float v0 = vs[k * QSTR + tn], v1 = vs[k * QSTR + tn + 16];
#pragma unroll
            for (int q = 0; q < 4; q++) {
                oacc[q][0] += pv[q] * v0;
                oacc[q][1] += pv[q] * v1;
            }
        }
#pragma unroll
        for (int q = 0; q < 4; q++) {
            Os[(tm + 16 * q) * XSTR + hd * 32 + tn] = oacc[q][0];
            Os[(tm + 16 * q) * XSTR + hd * 32 + tn + 16] = oacc[q][1];
        }
        __syncthreads();
    }
    // proj + residual
    float pacc[4][12];
#pragma unroll
    for (int q = 0; q < 4; q++)
#pragma unroll
        for (int u = 0; u < 12; u++) pacc[q][u] = proj_b[tn * 12 + u];
    for (int k = 0; k < 192; k++) {
        float ov[4];
#pragma unroll
        for (int q = 0; q < 4; q++) ov[q] = Os[(tm + 16 * q) * XSTR + k];
        const float* wr = proj_w + (size_t)k * 192 + tn * 12;
        float4 w0 = *(const float4*)wr;
        float4 w1 = *(const float4*)(wr + 4);
        float4 w2 = *(const float4*)(wr + 8);
#pragma unroll
        for (int q = 0; q < 4; q++) {
            pacc[q][0] += ov[q] * w0.x; pacc[q][1] += ov[q] * w0.y;
            pacc[q][2] += ov[q] * w0.z; pacc[q][3] += ov[q] * w0.w;
            pacc[q][4] += ov[q] * w1.x; pacc[q][5] += ov[q] * w1.y;
            pacc[q][6] += ov[q] * w1.z; pacc[q][7] += ov[q] * w1.w;
            pacc[q][8] += ov[q] * w2.x; pacc[q][9] += ov[q] * w2.y;
            pacc[q][10] += ov[q] * w2.z; pacc[q][11] += ov[q] * w2.w;
        }
    }
#pragma unroll
    for (int q = 0; q < 4; q++) {
        int n = tm + 16 * q;
        int yy = ((wh << 3) + (n >> 3) + SHIFT_) & 127;
        int xx = ((ww << 3) + (n & 7) + SHIFT_) & 127;
        size_t l = (size_t)b * LL + yy * WS + xx;
        const float* xp = x + l * CC + tn * 12;
        float* op = x1 + l * CC + tn * 12;
#pragma unroll
        for (int u = 0; u < 12; u++) op[u] = xp[u] + pacc[q][u];
    }
}

// ---------------- LeFF l1 + exact gelu (per image) ----------------
__global__ __launch_bounds__(256, 2) void k_l1(const float* __restrict__ h2,
                                               const float* __restrict__ w,
                                               const float* __restrict__ bias,
                                               float* __restrict__ t1, int b) {
    __shared__ float Xs[64 * XSTR];
    int mt = blockIdx.x % 256;
    int nt = blockIdx.x / 256;
    int tid = threadIdx.x, tn = tid & 15, tm = tid >> 4;
    for (int i = tid; i < 64 * 48; i += 256) {
        int n = i / 48, seg = i % 48;
        *(float4*)&Xs[n * XSTR + seg * 4] =
            *(const float4*)&h2[((size_t)b * LL + mt * 64 + n) * CC + seg * 4];
    }
    __syncthreads();
    float acc[4][4];
#pragma unroll
    for (int q = 0; q < 4; q++)
#pragma unroll
        for (int u = 0; u < 4; u++) acc[q][u] = bias[nt * 64 + tn * 4 + u];
    for (int k = 0; k < 192; k++) {
        float xv[4];
#pragma unroll
        for (int q = 0; q < 4; q++) xv[q] = Xs[(tm + 16 * q) * XSTR + k];
        float4 wv = *(const float4*)&w[(size_t)k * HIDD + nt * 64 + tn * 4];
#pragma unroll
        for (int q = 0; q < 4; q++) {
            acc[q][0] += xv[q] * wv.x; acc[q][1] += xv[q] * wv.y;
            acc[q][2] += xv[q] * wv.z; acc[q][3] += xv[q] * wv.w;
        }
    }
#pragma unroll
    for (int q = 0; q < 4; q++) {
        int row = mt * 64 + tm + 16 * q;
        float4 r;
        float v;
        v = acc[q][0]; r.x = 0.5f * v * (1.f + erff(v * 0.70710678118654752f));
        v = acc[q][1]; r.y = 0.5f * v * (1.f + erff(v * 0.70710678118654752f));
        v = acc[q][2]; r.z = 0.5f * v * (1.f + erff(v * 0.70710678118654752f));
        v = acc[q][3]; r.w = 0.5f * v * (1.f + erff(v * 0.70710678118654752f));
        *(float4*)&t1[(size_t)row * HIDD + nt * 64 + tn * 4] = r;
    }
}

// ---------------- LeFF dwconv + gelu + l2 + residual (per image) ----------------
#define DSTR 260
__global__ __launch_bounds__(256, 2) void k_dwl2(
    const float* __restrict__ t1, const float* __restrict__ dww,
    const float* __restrict__ dwb, const float* __restrict__ l2w,
    const float* __restrict__ l2b, const float* __restrict__ x1,
    float* __restrict__ out, int b) {
    __shared__ float patch[36 * DSTR];
    __shared__ float gt[16 * DSTR];
    int blk = blockIdx.x;
    int tx = blk & 31, ty = blk >> 5;
    int tid = threadIdx.x, tn = tid & 15, tm = tid >> 4;
    float acc[12];
#pragma unroll
    for (int u = 0; u < 12; u++) acc[u] = l2b[tn * 12 + u];
    for (int jc = 0; jc < 3; jc++) {
        // stage 6x6 x 256ch patch of t1
        for (int i = tid; i < 36 * 64; i += 256) {
            int pos = i >> 6, seg = i & 63;
            int py = pos / 6, px = pos % 6;
            int gy = ty * 4 + py - 1, gx = tx * 4 + px - 1;
            float4 v = make_float4(0.f, 0.f, 0.f, 0.f);
            if (gy >= 0 && gy < HS && gx >= 0 && gx < WS)
                v = *(const float4*)&t1[((size_t)(gy * WS + gx)) * HIDD + jc * 256 + seg * 4];
            *(float4*)&patch[pos * DSTR + seg * 4] = v;
        }
        __syncthreads();
        // depthwise 3x3 + gelu
        {
            int p = tid & 15, cg = tid >> 4;
            int pi = p >> 2, pj = p & 3;
#pragma unroll
            for (int v = 0; v < 16; v++) {
                int ch = cg * 16 + v;
                int gch = jc * 256 + ch;
                float u = dwb[gch];
#pragma unroll
                for (int dy = 0; dy < 3; dy++)
#pragma unroll
                    for (int dx = 0; dx < 3; dx++)
                        u += patch[((pi + dy) * 6 + pj + dx) * DSTR + ch] *
                             dww[gch * 9 + dy * 3 + dx];
                gt[p * DSTR + ch] = 0.5f * u * (1.f + erff(u * 0.70710678118654752f));
            }
        }
        __syncthreads();
        // accumulate g @ l2_w
        for (int k = 0; k < 256; k++) {
            float gv = gt[tm * DSTR + k];
            const float* wr = l2w + (size_t)(jc * 256 + k) * CC + tn * 12;
            float4 w0 = *(const float4*)wr;
            float4 w1 = *(const float4*)(wr + 4);
            float4 w2 = *(const float4*)(wr + 8);
            acc[0] += gv * w0.x; acc[1] += gv * w0.y; acc[2] += gv * w0.z; acc[3] += gv * w0.w;
            acc[4] += gv * w1.x; acc[5] += gv * w1.y; acc[6] += gv * w1.z; acc[7] += gv * w1.w;
            acc[8] += gv * w2.x; acc[9] += gv * w2.y; acc[10] += gv * w2.z; acc[11] += gv * w2.w;
        }
        __syncthreads();
    }
    int pi = tm >> 2, pj = tm & 3;
    size_t l = (size_t)b * LL + (ty * 4 + pi) * WS + tx * 4 + pj;
    const float* xp = x1 + l * CC + tn * 12;
    float* op = out + l * CC + tn * 12;
#pragma unroll
    for (int u = 0; u < 12; u++) op[u] = xp[u] + acc[u];
}

// ---------------- launch ----------------
extern "C" void kernel_launch(void* const* d_in, const int* in_sizes, int n_in,
                              void* d_out, int out_size, void* d_ws, size_t ws_size,
                              hipStream_t stream) {
    const float* x = (const float*)d_in[0];
    const float* src = (const float*)d_in[1];
    const float* ln1_g = (const float*)d_in[2];
    const float* ln1_b = (const float*)d_in[3];
    const float* s1_w1 = (const float*)d_in[4];
    const float* s1_b1 = (const float*)d_in[5];
    const float* s1_wg = (const float*)d_in[6];
    const float* s1_bg = (const float*)d_in[7];
    const float* s1_wb = (const float*)d_in[8];
    const float* s1_bb = (const float*)d_in[9];
    const float* qkv_w = (const float*)d_in[10];
    const float* qkv_b = (const float*)d_in[11];
    const float* rpb = (const float*)d_in[12];
    const float* proj_w = (const float*)d_in[13];
    const float* proj_b = (const float*)d_in[14];
    const float* ln2_g = (const float*)d_in[15];
    const float* ln2_b = (const float*)d_in[16];
    const float* s2_w1 = (const float*)d_in[17];
    const float* s2_b1 = (const float*)d_in[18];
    const float* s2_wg = (const float*)d_in[19];
    const float* s2_bg = (const float*)d_in[20];
    const float* s2_wb = (const float*)d_in[21];
    const float* s2_bb = (const float*)d_in[22];
    const float* l1_w = (const float*)d_in[23];
    const float* l1_b = (const float*)d_in[24];
    const float* dw_w = (const float*)d_in[25];
    const float* dw_b = (const float*)d_in[26];
    const float* l2_w = (const float*)d_in[27];
    const float* l2_b = (const float*)d_in[28];
    float* out = (float*)d_out;

    float* wt1 = (float*)d_ws;
    float* wt2 = wt1 + 442368;
    float* a = wt2 + 442368;
    float* hbuf = a + 16777216;
    float* x1 = hbuf + 25165824;
    float* mub = x1 + 25165824;
    float* rsb = mub + 131072;
    float* t1 = rsb + 131072;

    k_trans_w<<<(1152 * 384 + 255) / 256, 256, 0, stream>>>(s1_wg, s1_wb, wt1);
    k_trans_w<<<(1152 * 384 + 255) / 256, 256, 0, stream>>>(s2_wg, s2_wb, wt2);

    // SPADE 1
    k_conv1<<<BB * HS * (WS / 16), 128, 0, stream>>>(src, s1_w1, s1_b1, a);
    k_lnstats<<<BB * LL / 4, 256, 0, stream>>>(x, mub, rsb);
    k_spade<<<BB * 256, 256, 0, stream>>>(x, mub, rsb, ln1_g, ln1_b, s1_bg, s1_bb, a, wt1, hbuf);

    // attention + residual
    k_attn<<<BB * 256, 256, 0, stream>>>(hbuf, x, qkv_w, qkv_b, rpb, proj_w, proj_b, x1);

    // SPADE 2
    k_conv1<<<BB * HS * (WS / 16), 128, 0, stream>>>(src, s2_w1, s2_b1, a);
    k_lnstats<<<BB * LL / 4, 256, 0, stream>>>(x1, mub, rsb);
    k_spade<<<BB * 256, 256, 0, stream>>>(x1, mub, rsb, ln2_g, ln2_b, s2_bg, s2_bb, a, wt2, hbuf);

    // LeFF per image
    for (int b = 0; b < BB; b++) {
        k_l1<<<256 * 12, 256, 0, stream>>>(hbuf, l1_w, l1_b, t1, b);
        k_dwl2<<<1024, 256, 0, stream>>>(t1, dw_w, dw_b, l2_w, l2_b, x1, out, b);
    }
}

// Round 4
// 5199.191 us; speedup vs baseline: 1.7719x; 1.7719x over previous
//
#include <hip/hip_runtime.h>
#include <hip/hip_bf16.h>
#include <cmath>

#define BB 8
#define HS 128
#define WS 128
#define CC 192
#define NHEAD 6
#define WIN 8
#define SHIFT_ 4
#define LL (HS*WS)
#define HIDD (4*CC)

using frag_ab = __attribute__((ext_vector_type(8))) short;   // 8 bf16
using frag_cd = __attribute__((ext_vector_type(4))) float;   // 4 f32
static_assert(sizeof(frag_ab) == 16, "frag_ab must be 16B");

// ---------------- weight transpose for spade convs (bf16, MFMA-B layout) ----------------
// dest: wB[((k>>3)*384 + c)*8 + (k&7)], k = tap*128 + ch, c in [0,384): c<192 -> wg, else wb
__global__ void k_trans_w(const float* __restrict__ wg, const float* __restrict__ wb,
                          __hip_bfloat16* __restrict__ wB) {
    int idx = blockIdx.x * 256 + threadIdx.x;
    if (idx >= 1152 * 384) return;
    int k7 = idx & 7;
    int rest = idx >> 3;
    int c = rest % 384;
    int kg = rest / 384;
    int k = kg * 8 + k7;
    int tap = k >> 7;
    int ch = k & 127;
    const float* srcp = (c < 192) ? wg : wb;
    int cc = (c < 192) ? c : (c - 192);
    wB[idx] = __float2bfloat16(srcp[(cc * 128 + ch) * 9 + tap]);
}

// ---------------- conv1: src [B,1,H,W] -> a [B,H,W,128] bf16, leaky_relu ----------------
__global__ void k_conv1(const float* __restrict__ src, const float* __restrict__ w1,
                        const float* __restrict__ b1, __hip_bfloat16* __restrict__ a) {
    int c = threadIdx.x;               // 128 threads
    int blk = blockIdx.x;              // b*Hs*(Ws/16)
    int xseg = blk % (WS / 16);
    int tmp = blk / (WS / 16);
    int y = tmp % HS;
    int b = tmp / HS;
    float w[9];
#pragma unroll
    for (int t = 0; t < 9; t++) w[t] = w1[c * 9 + t];
    float bias = b1[c];
    const float* sp = src + (size_t)b * HS * WS;
    for (int px = 0; px < 16; px++) {
        int x = xseg * 16 + px;
        float acc = bias;
#pragma unroll
        for (int dy = 0; dy < 3; dy++) {
            int yy = y + dy - 1;
            if (yy < 0 || yy >= HS) continue;
#pragma unroll
            for (int dx = 0; dx < 3; dx++) {
                int xx = x + dx - 1;
                if (xx < 0 || xx >= WS) continue;
                acc += sp[yy * WS + xx] * w[dy * 3 + dx];
            }
        }
        float r = acc > 0.f ? acc : 0.01f * acc;
        a[(((size_t)b * HS + y) * WS + x) * 128 + c] = __float2bfloat16(r);
    }
}

// ---------------- LN stats per token ----------------
__global__ void k_lnstats(const float* __restrict__ x, float* __restrict__ mu,
                          float* __restrict__ rs) {
    int tok = blockIdx.x * 4 + (threadIdx.x >> 6);
    int lane = threadIdx.x & 63;
    const float* xp = x + (size_t)tok * CC;
    float v0 = xp[lane], v1 = xp[lane + 64], v2 = xp[lane + 128];
    float s = v0 + v1 + v2;
#pragma unroll
    for (int off = 32; off; off >>= 1) s += __shfl_xor(s, off);
    float m = s * (1.f / CC);
    float e0 = v0 - m, e1 = v1 - m, e2 = v2 - m;
    float s2 = e0 * e0 + e1 * e1 + e2 * e2;
#pragma unroll
    for (int off = 32; off; off >>= 1) s2 += __shfl_xor(s2, off);
    if (lane == 0) {
        mu[tok] = m;
        rs[tok] = rsqrtf(s2 * (1.f / CC) + 1e-5f);
    }
}

// ---------------- fused SPADE via MFMA: h = ln(x)*(1+gamma)+beta ----------------
// block = 256 thr = 4 waves; tile M=64 px (8x8 window), N=384 (gamma||beta), K=1152.
// Wave w: gamma cols [w*48, w*48+48), beta cols [192+w*48, ...).
// A: bf16 LDS patch [100 pos][136], linear + 8-short row pad.
// B: global bf16, layout [(k>>3)*384 + c][k&7] -> lane reads 16B contiguous.
#define PST 136
__global__ __launch_bounds__(256, 2) void k_spade(
    const float* __restrict__ x, const float* __restrict__ mu, const float* __restrict__ rs,
    const float* __restrict__ g, const float* __restrict__ bta,
    const float* __restrict__ bg, const float* __restrict__ bb,
    const __hip_bfloat16* __restrict__ a, const __hip_bfloat16* __restrict__ wB,
    float* __restrict__ h) {
    __shared__ __align__(16) short patch[100 * PST];   // 27.2 KB bf16
    int blk = blockIdx.x;
    int bx = blk & 15;
    int by = (blk >> 4) & 15;
    int b = blk >> 8;
    int tid = threadIdx.x;
    // stage 10x10x128 bf16 patch (linear, padded rows)
    const short* ab = (const short*)a;
    for (int i = tid; i < 1600; i += 256) {
        int pos = i >> 4, gseg = i & 15;
        int py = pos / 10, px_ = pos % 10;
        int gy = by * 8 + py - 1, gx = bx * 8 + px_ - 1;
        frag_ab v = {};
        if (gy >= 0 && gy < HS && gx >= 0 && gx < WS)
            v = *(const frag_ab*)&ab[(((size_t)b * HS + gy) * WS + gx) * 128 + gseg * 8];
        *(frag_ab*)&patch[pos * PST + gseg * 8] = v;
    }
    __syncthreads();

    int lane = tid & 63, wid = tid >> 6;
    int lr = lane & 15, lg = lane >> 4;
    frag_cd accg[4][3], accb[4][3];
#pragma unroll
    for (int mf = 0; mf < 4; mf++)
#pragma unroll
        for (int j = 0; j < 3; j++) {
            accg[mf][j] = (frag_cd){0.f, 0.f, 0.f, 0.f};
            accb[mf][j] = (frag_cd){0.f, 0.f, 0.f, 0.f};
        }
    int colg = wid * 48 + lr;       // gamma col for this lane (j adds 16)
    const short* wBs = (const short*)wB;

    for (int tap = 0; tap < 9; ++tap) {
        int dy = tap / 3, dx = tap % 3;
        int pos[4];
#pragma unroll
        for (int mf = 0; mf < 4; mf++) {
            int p = mf * 16 + lr;
            pos[mf] = ((p >> 3) + dy) * 10 + (p & 7) + dx;
        }
#pragma unroll
        for (int k4 = 0; k4 < 4; ++k4) {
            int gk = k4 * 4 + lg;              // granule within 128ch (0..15)
            frag_ab af[4];
#pragma unroll
            for (int mf = 0; mf < 4; mf++)
                af[mf] = *(const frag_ab*)&patch[pos[mf] * PST + gk * 8];
            int kgrp = tap * 16 + gk;          // global 8-k group
            const short* wrow = wBs + (size_t)(kgrp * 384) * 8;
            frag_ab bf[6];
#pragma unroll
            for (int j = 0; j < 3; j++) {
                bf[j]     = *(const frag_ab*)&wrow[(colg + j * 16) * 8];
                bf[j + 3] = *(const frag_ab*)&wrow[(192 + colg + j * 16) * 8];
            }
#pragma unroll
            for (int mf = 0; mf < 4; mf++)
#pragma unroll
                for (int j = 0; j < 3; j++) {
                    accg[mf][j] = __builtin_amdgcn_mfma_f32_16x16x32_bf16(
                        af[mf], bf[j], accg[mf][j], 0, 0, 0);
                    accb[mf][j] = __builtin_amdgcn_mfma_f32_16x16x32_bf16(
                        af[mf], bf[j + 3], accb[mf][j], 0, 0, 0);
                }
        }
    }
    // epilogue: D[px][col] at row = lg*4 + r, col = lr (within 16x16 frag)
#pragma unroll
    for (int mf = 0; mf < 4; mf++)
#pragma unroll
        for (int r = 0; r < 4; r++) {
            int p = mf * 16 + lg * 4 + r;
            int gy = by * 8 + (p >> 3), gx = bx * 8 + (p & 7);
            size_t loc = (size_t)b * LL + gy * WS + gx;
            float m = mu[loc], rv = rs[loc];
            const float* xp = x + loc * CC;
            float* hp = h + loc * CC;
#pragma unroll
            for (int j = 0; j < 3; j++) {
                int c = colg + j * 16;
                float gm = accg[mf][j][r] + bg[c];
                float bt = accb[mf][j][r] + bb[c];
                float n = (xp[c] - m) * rv * g[c] + bta[c];
                hp[c] = n * (1.f + gm) + bt;
            }
        }
}

// ---------------- fused window attention + proj + residual ----------------
#define XSTR 196
#define QSTR 36
#define SSTR 68
__global__ __launch_bounds__(256, 1) void k_attn(
    const float* __restrict__ h, const float* __restrict__ x,
    const float* __restrict__ qkv_w, const float* __restrict__ qkv_b,
    const float* __restrict__ rpb, const float* __restrict__ proj_w,
    const float* __restrict__ proj_b, float* __restrict__ x1) {
    __shared__ float Xs[64 * XSTR];
    __shared__ float Os[64 * XSTR];
    __shared__ float qs[64 * QSTR];
    __shared__ float ks_[64 * QSTR];
    __shared__ float vs[64 * QSTR];
    __shared__ float ss[64 * SSTR];
    int blk = blockIdx.x;
    int ww = blk & 15, wh = (blk >> 4) & 15, b = blk >> 8;
    int tid = threadIdx.x, tn = tid & 15, tm = tid >> 4;
    // stage X (shifted window gather)
    for (int i = tid; i < 64 * 48; i += 256) {
        int n = i / 48, seg = i % 48;
        int yy = ((wh << 3) + (n >> 3) + SHIFT_) & 127;
        int xx = ((ww << 3) + (n & 7) + SHIFT_) & 127;
        *(float4*)&Xs[n * XSTR + seg * 4] =
            *(const float4*)&h[((size_t)b * LL + yy * WS + xx) * CC + seg * 4];
    }
    __syncthreads();
    for (int hd = 0; hd < NHEAD; hd++) {
        // qkv for this head
        float acc[4][6];
#pragma unroll
        for (int q = 0; q < 4; q++)
#pragma unroll
            for (int u = 0; u < 6; u++)
                acc[q][u] = qkv_b[(u >> 1) * 192 + hd * 32 + tn + ((u & 1) << 4)];
        for (int k = 0; k < 192; k++) {
            float xv[4];
#pragma unroll
            for (int q = 0; q < 4; q++) xv[q] = Xs[(tm + 16 * q) * XSTR + k];
            const float* wr = qkv_w + (size_t)k * 576 + hd * 32 + tn;
            float w0 = wr[0], w1 = wr[16], w2 = wr[192], w3 = wr[208], w4 = wr[384], w5 = wr[400];
#pragma unroll
            for (int q = 0; q < 4; q++) {
                acc[q][0] += xv[q] * w0; acc[q][1] += xv[q] * w1;
                acc[q][2] += xv[q] * w2; acc[q][3] += xv[q] * w3;
                acc[q][4] += xv[q] * w4; acc[q][5] += xv[q] * w5;
            }
        }
#pragma unroll
        for (int q = 0; q < 4; q++) {
            int row = tm + 16 * q;
            qs[row * QSTR + tn] = acc[q][0] * 0.17677669529663687f;
            qs[row * QSTR + tn + 16] = acc[q][1] * 0.17677669529663687f;
            ks_[row * QSTR + tn] = acc[q][2];
            ks_[row * QSTR + tn + 16] = acc[q][3];
            vs[row * QSTR + tn] = acc[q][4];
            vs[row * QSTR + tn + 16] = acc[q][5];
        }
        __syncthreads();
        // scores + rpb + mask
        float sacc[4][4] = {};
        for (int k = 0; k < 32; k++) {
            float qv[4], kv[4];
#pragma unroll
            for (int q = 0; q < 4; q++) qv[q] = qs[(tm + 16 * q) * QSTR + k];
#pragma unroll
            for (int u = 0; u < 4; u++) kv[u] = ks_[(tn + 16 * u) * QSTR + k];
#pragma unroll
            for (int q = 0; q < 4; q++)
#pragma unroll
                for (int u = 0; u < 4; u++) sacc[q][u] += qv[q] * kv[u];
        }
#pragma unroll
        for (int q = 0; q < 4; q++) {
            int n = tm + 16 * q;
            int i1 = n >> 3, j1 = n & 7;
            int yr1 = (wh << 3) + i1, xr1 = (ww << 3) + j1;
            int lh1 = (yr1 < 120) ? 0 : ((yr1 < 124) ? 1 : 2);
            int lw1 = (xr1 < 120) ? 0 : ((xr1 < 124) ? 1 : 2);
#pragma unroll
            for (int u = 0; u < 4; u++) {
                int m = tn + 16 * u;
                int i2 = m >> 3, j2 = m & 7;
                int rel = (i1 - i2 + 7) * 15 + (j1 - j2 + 7);
                float bias = rpb[rel * NHEAD + hd];
                int yr2 = (wh << 3) + i2, xr2 = (ww << 3) + j2;
                int lh2 = (yr2 < 120) ? 0 : ((yr2 < 124) ? 1 : 2);
                int lw2 = (xr2 < 120) ? 0 : ((xr2 < 124) ? 1 : 2);
                float msk = (lh1 == lh2 && lw1 == lw2) ? 0.f : -100.f;
                ss[n * SSTR + m] = sacc[q][u] + bias + msk;
            }
        }
        __syncthreads();
        // softmax (4 lanes per row)
        {
            int r = tid >> 2, lg2 = tid & 3;
            float ev[16];
            float mx = -3.4e38f;
#pragma unroll
            for (int t = 0; t < 16; t++) {
                ev[t] = ss[r * SSTR + lg2 + 4 * t];
                mx = fmaxf(mx, ev[t]);
            }
            mx = fmaxf(mx, __shfl_xor(mx, 1));
            mx = fmaxf(mx, __shfl_xor(mx, 2));
            float sm = 0.f;
#pragma unroll
            for (int t = 0; t < 16; t++) {
                ev[t] = expf(ev[t] - mx);
                sm += ev[t];
            }
            sm += __shfl_xor(sm, 1);
            sm += __shfl_xor(sm, 2);
            float inv = 1.f / sm;
#pragma unroll
            for (int t = 0; t < 16; t++) ss[r * SSTR + lg2 + 4 * t] = ev[t] * inv;
        }
        __syncthreads();
        // PV
        float oacc[4][2] = {};
        for (int k = 0; k < 64; k++) {
            float pv[4];
#pragma unroll
            for (int q = 0; q < 4; q++) pv[q] = ss[(tm + 16 * q) * SSTR + k];
            float v0 = vs[k * QSTR + tn], v1 = vs[k * QSTR + tn + 16];
#pragma unroll
            for (int q = 0; q < 4; q++) {
                oacc[q][0] += pv[q] * v0;
                oacc[q][1] += pv[q] * v1;
            }
        }
#pragma unroll
        for (int q = 0; q < 4; q++) {
            Os[(tm + 16 * q) * XSTR + hd * 32 + tn] = oacc[q][0];
            Os[(tm + 16 * q) * XSTR + hd * 32 + tn + 16] = oacc[q][1];
        }
        __syncthreads();
    }
    // proj + residual
    float pacc[4][12];
#pragma unroll
    for (int q = 0; q < 4; q++)
#pragma unroll
        for (int u = 0; u < 12; u++) pacc[q][u] = proj_b[tn * 12 + u];
    for (int k = 0; k < 192; k++) {
        float ov[4];
#pragma unroll
        for (int q = 0; q < 4; q++) ov[q] = Os[(tm + 16 * q) * XSTR + k];
        const float* wr = proj_w + (size_t)k * 192 + tn * 12;
        float4 w0 = *(const float4*)wr;
        float4 w1 = *(const float4*)(wr + 4);
        float4 w2 = *(const float4*)(wr + 8);
#pragma unroll
        for (int q = 0; q < 4; q++) {
            pacc[q][0] += ov[q] * w0.x; pacc[q][1] += ov[q] * w0.y;
            pacc[q][2] += ov[q] * w0.z; pacc[q][3] += ov[q] * w0.w;
            pacc[q][4] += ov[q] * w1.x; pacc[q][5] += ov[q] * w1.y;
            pacc[q][6] += ov[q] * w1.z; pacc[q][7] += ov[q] * w1.w;
            pacc[q][8] += ov[q] * w2.x; pacc[q][9] += ov[q] * w2.y;
            pacc[q][10] += ov[q] * w2.z; pacc[q][11] += ov[q] * w2.w;
        }
    }
#pragma unroll
    for (int q = 0; q < 4; q++) {
        int n = tm + 16 * q;
        int yy = ((wh << 3) + (n >> 3) + SHIFT_) & 127;
        int xx = ((ww << 3) + (n & 7) + SHIFT_) & 127;
        size_t l = (size_t)b * LL + yy * WS + xx;
        const float* xp = x + l * CC + tn * 12;
        float* op = x1 + l * CC + tn * 12;
#pragma unroll
        for (int u = 0; u < 12; u++) op[u] = xp[u] + pacc[q][u];
    }
}

// ---------------- LeFF l1 + exact gelu (per image) ----------------
__global__ __launch_bounds__(256, 2) void k_l1(const float* __restrict__ h2,
                                               const float* __restrict__ w,
                                               const float* __restrict__ bias,
                                               float* __restrict__ t1, int b) {
    __shared__ float Xs[64 * XSTR];
    int mt = blockIdx.x % 256;
    int nt = blockIdx.x / 256;
    int tid = threadIdx.x, tn = tid & 15, tm = tid >> 4;
    for (int i = tid; i < 64 * 48; i += 256) {
        int n = i / 48, seg = i % 48;
        *(float4*)&Xs[n * XSTR + seg * 4] =
            *(const float4*)&h2[((size_t)b * LL + mt * 64 + n) * CC + seg * 4];
    }
    __syncthreads();
    float acc[4][4];
#pragma unroll
    for (int q = 0; q < 4; q++)
#pragma unroll
        for (int u = 0; u < 4; u++) acc[q][u] = bias[nt * 64 + tn * 4 + u];
    for (int k = 0; k < 192; k++) {
        float xv[4];
#pragma unroll
        for (int q = 0; q < 4; q++) xv[q] = Xs[(tm + 16 * q) * XSTR + k];
        float4 wv = *(const float4*)&w[(size_t)k * HIDD + nt * 64 + tn * 4];
#pragma unroll
        for (int q = 0; q < 4; q++) {
            acc[q][0] += xv[q] * wv.x; acc[q][1] += xv[q] * wv.y;
            acc[q][2] += xv[q] * wv.z; acc[q][3] += xv[q] * wv.w;
        }
    }
#pragma unroll
    for (int q = 0; q < 4; q++) {
        int row = mt * 64 + tm + 16 * q;
        float4 r;
        float v;
        v = acc[q][0]; r.x = 0.5f * v * (1.f + erff(v * 0.70710678118654752f));
        v = acc[q][1]; r.y = 0.5f * v * (1.f + erff(v * 0.70710678118654752f));
        v = acc[q][2]; r.z = 0.5f * v * (1.f + erff(v * 0.70710678118654752f));
        v = acc[q][3]; r.w = 0.5f * v * (1.f + erff(v * 0.70710678118654752f));
        *(float4*)&t1[(size_t)row * HIDD + nt * 64 + tn * 4] = r;
    }
}

// ---------------- LeFF dwconv + gelu + l2 + residual (per image) ----------------
#define DSTR 260
__global__ __launch_bounds__(256, 2) void k_dwl2(
    const float* __restrict__ t1, const float* __restrict__ dww,
    const float* __restrict__ dwb, const float* __restrict__ l2w,
    const float* __restrict__ l2b, const float* __restrict__ x1,
    float* __restrict__ out, int b) {
    __shared__ float patch[36 * DSTR];
    __shared__ float gt[16 * DSTR];
    int blk = blockIdx.x;
    int tx = blk & 31, ty = blk >> 5;
    int tid = threadIdx.x, tn = tid & 15, tm = tid >> 4;
    float acc[12];
#pragma unroll
    for (int u = 0; u < 12; u++) acc[u] = l2b[tn * 12 + u];
    for (int jc = 0; jc < 3; jc++) {
        // stage 6x6 x 256ch patch of t1
        for (int i = tid; i < 36 * 64; i += 256) {
            int pos = i >> 6, seg = i & 63;
            int py = pos / 6, px = pos % 6;
            int gy = ty * 4 + py - 1, gx = tx * 4 + px - 1;
            float4 v = make_float4(0.f, 0.f, 0.f, 0.f);
            if (gy >= 0 && gy < HS && gx >= 0 && gx < WS)
                v = *(const float4*)&t1[((size_t)(gy * WS + gx)) * HIDD + jc * 256 + seg * 4];
            *(float4*)&patch[pos * DSTR + seg * 4] = v;
        }
        __syncthreads();
        // depthwise 3x3 + gelu
        {
            int p = tid & 15, cg = tid >> 4;
            int pi = p >> 2, pj = p & 3;
#pragma unroll
            for (int v = 0; v < 16; v++) {
                int ch = cg * 16 + v;
                int gch = jc * 256 + ch;
                float u = dwb[gch];
#pragma unroll
                for (int dy = 0; dy < 3; dy++)
#pragma unroll
                    for (int dx = 0; dx < 3; dx++)
                        u += patch[((pi + dy) * 6 + pj + dx) * DSTR + ch] *
                             dww[gch * 9 + dy * 3 + dx];
                gt[p * DSTR + ch] = 0.5f * u * (1.f + erff(u * 0.70710678118654752f));
            }
        }
        __syncthreads();
        // accumulate g @ l2_w
        for (int k = 0; k < 256; k++) {
            float gv = gt[tm * DSTR + k];
            const float* wr = l2w + (size_t)(jc * 256 + k) * CC + tn * 12;
            float4 w0 = *(const float4*)wr;
            float4 w1 = *(const float4*)(wr + 4);
            float4 w2 = *(const float4*)(wr + 8);
            acc[0] += gv * w0.x; acc[1] += gv * w0.y; acc[2] += gv * w0.z; acc[3] += gv * w0.w;
            acc[4] += gv * w1.x; acc[5] += gv * w1.y; acc[6] += gv * w1.z; acc[7] += gv * w1.w;
            acc[8] += gv * w2.x; acc[9] += gv * w2.y; acc[10] += gv * w2.z; acc[11] += gv * w2.w;
        }
        __syncthreads();
    }
    int pi = tm >> 2, pj = tm & 3;
    size_t l = (size_t)b * LL + (ty * 4 + pi) * WS + tx * 4 + pj;
    const float* xp = x1 + l * CC + tn * 12;
    float* op = out + l * CC + tn * 12;
#pragma unroll
    for (int u = 0; u < 12; u++) op[u] = xp[u] + acc[u];
}

// ---------------- launch ----------------
extern "C" void kernel_launch(void* const* d_in, const int* in_sizes, int n_in,
                              void* d_out, int out_size, void* d_ws, size_t ws_size,
                              hipStream_t stream) {
    const float* x = (const float*)d_in[0];
    const float* src = (const float*)d_in[1];
    const float* ln1_g = (const float*)d_in[2];
    const float* ln1_b = (const float*)d_in[3];
    const float* s1_w1 = (const float*)d_in[4];
    const float* s1_b1 = (const float*)d_in[5];
    const float* s1_wg = (const float*)d_in[6];
    const float* s1_bg = (const float*)d_in[7];
    const float* s1_wb = (const float*)d_in[8];
    const float* s1_bb = (const float*)d_in[9];
    const float* qkv_w = (const float*)d_in[10];
    const float* qkv_b = (const float*)d_in[11];
    const float* rpb = (const float*)d_in[12];
    const float* proj_w = (const float*)d_in[13];
    const float* proj_b = (const float*)d_in[14];
    const float* ln2_g = (const float*)d_in[15];
    const float* ln2_b = (const float*)d_in[16];
    const float* s2_w1 = (const float*)d_in[17];
    const float* s2_b1 = (const float*)d_in[18];
    const float* s2_wg = (const float*)d_in[19];
    const float* s2_bg = (const float*)d_in[20];
    const float* s2_wb = (const float*)d_in[21];
    const float* s2_bb = (const float*)d_in[22];
    const float* l1_w = (const float*)d_in[23];
    const float* l1_b = (const float*)d_in[24];
    const float* dw_w = (const float*)d_in[25];
    const float* dw_b = (const float*)d_in[26];
    const float* l2_w = (const float*)d_in[27];
    const float* l2_b = (const float*)d_in[28];
    float* out = (float*)d_out;

    // Workspace map (BYTES). R2/R3 BUG was here: hbuf/x1 are [B,L,C] fp32 =
    // 100663296 B each, NOT 50331648 — x1 overlapped hbuf's top half.
    char* wsb = (char*)d_ws;
    __hip_bfloat16* wB1 = (__hip_bfloat16*)(wsb);                   //       0, 884736 B
    __hip_bfloat16* wB2 = (__hip_bfloat16*)(wsb + 884736);          //  884736, 884736 B
    __hip_bfloat16* a   = (__hip_bfloat16*)(wsb + 1769472);         // 1769472, 33554432 B
    float* hbuf = (float*)(wsb + 35323904);                         // 100663296 B
    float* x1   = (float*)(wsb + 135987200);                        // 100663296 B
    float* mub  = (float*)(wsb + 236650496);                        // 524288 B
    float* rsb  = (float*)(wsb + 237174784);                        // 524288 B
    float* t1   = (float*)(wsb + 237699072);                        // 50331648 B (end 288030720)

    k_trans_w<<<1728, 256, 0, stream>>>(s1_wg, s1_wb, wB1);
    k_trans_w<<<1728, 256, 0, stream>>>(s2_wg, s2_wb, wB2);

    // SPADE 1
    k_conv1<<<BB * HS * (WS / 16), 128, 0, stream>>>(src, s1_w1, s1_b1, a);
    k_lnstats<<<BB * LL / 4, 256, 0, stream>>>(x, mub, rsb);
    k_spade<<<BB * 256, 256, 0, stream>>>(x, mub, rsb, ln1_g, ln1_b, s1_bg, s1_bb, a, wB1, hbuf);

    // attention + residual
    k_attn<<<BB * 256, 256, 0, stream>>>(hbuf, x, qkv_w, qkv_b, rpb, proj_w, proj_b, x1);

    // SPADE 2
    k_conv1<<<BB * HS * (WS / 16), 128, 0, stream>>>(src, s2_w1, s2_b1, a);
    k_lnstats<<<BB * LL / 4, 256, 0, stream>>>(x1, mub, rsb);
    k_spade<<<BB * 256, 256, 0, stream>>>(x1, mub, rsb, ln2_g, ln2_b, s2_bg, s2_bb, a, wB2, hbuf);

    // LeFF per image
    for (int b = 0; b < BB; b++) {
        k_l1<<<256 * 12, 256, 0, stream>>>(hbuf, l1_w, l1_b, t1, b);
        k_dwl2<<<1024, 256, 0, stream>>>(t1, dw_w, dw_b, l2_w, l2_b, x1, out, b);
    }
}